// Round 2
// baseline (142.786 us; speedup 1.0000x reference)
//
#include <hip/hip_runtime.h>
#include <math.h>

// Problem constants
#define BB 2
#define LL 128
#define HH 768
#define H2 1536          // 2*H
#define CC 6
#define NTOK (BB * LL)   // 256

// Workspace layout (float offsets)
#define WFC_OFF   0          // Wfc = Wf @ cls_w   (1536 x 6)
#define WFWFC_OFF 9216       // WfWfc = Wf @ Wfc   (1536 x 6)
#define SM_OFF    18432      // small matrices: K1=0 M3=36 M4=72 K2=108 M3f=144 M4f=180 d1=216 dbfc=222
#define TOK_OFF   18672      // 6 per-token arrays of NTOK*CC floats: 0:p 1:q 2:r1 3:r2 4:s1 5:s2

// ---------------------------------------------------------------------------
// Shared helper: 6-col matcol row + wave reduction, used inline below.

// N1: blocks 0..1535  -> Wfc row k  (feat_w row k  @ cls_w)
//     blocks 1536..1649 -> 114 dot tasks vs cls_w (K1, M3, M4, d1)
__global__ __launch_bounds__(256) void k1_wfc_dots(const float* __restrict__ feat_w,
                                                   const float* __restrict__ cls_w,
                                                   const float* __restrict__ cls_b,
                                                   const float* __restrict__ feat_b,
                                                   float* __restrict__ ws) {
    int blk = blockIdx.x, tid = threadIdx.x;
    int wave = tid >> 6, lane = tid & 63;
    if (blk < H2) {
        // Wfc row
        float acc[CC] = {};
        const float* arow = feat_w + (size_t)blk * H2;
        for (int r = tid; r < H2; r += 256) {
            float w = arow[r];
            const float* brow = cls_w + r * CC;
#pragma unroll
            for (int c = 0; c < CC; ++c) acc[c] += w * brow[c];
        }
#pragma unroll
        for (int c = 0; c < CC; ++c)
#pragma unroll
            for (int off = 32; off > 0; off >>= 1) acc[c] += __shfl_down(acc[c], off, 64);
        __shared__ float sred[4][CC];
        if (lane == 0)
#pragma unroll
            for (int c = 0; c < CC; ++c) sred[wave][c] = acc[c];
        __syncthreads();
        if (tid < CC)
            ws[WFC_OFF + blk * CC + tid] = sred[0][tid] + sred[1][tid] + sred[2][tid] + sred[3][tid];
    } else {
        // dot tasks vs cls_w
        int task = blk - H2;   // 0..113
        const float* va;
        int c, outIdx;
        bool add_clsb = false;
        if (task < 108) {
            int m = task / 36, e = task % 36, cp = e / CC;
            c = e % CC;
            int row = (m == 0) ? (H2 + 2 * CC) : ((m == 1) ? H2 : (H2 + CC)); // K1:W5, M3:W3, M4:W4
            va = feat_w + (size_t)(row + cp) * H2;
            outIdx = m * 36 + e;
        } else {
            c = task - 108;
            va = feat_b;
            outIdx = 216 + c;
            add_clsb = true;
        }
        float acc = 0.f;
        for (int r = tid; r < H2; r += 256) acc += va[r] * cls_w[r * CC + c];
#pragma unroll
        for (int off = 32; off > 0; off >>= 1) acc += __shfl_down(acc, off, 64);
        __shared__ float sred1[4];
        if (lane == 0) sred1[wave] = acc;
        __syncthreads();
        if (tid == 0) {
            float v = sred1[0] + sred1[1] + sred1[2] + sred1[3];
            if (add_clsb) v += cls_b[c];
            ws[SM_OFF + outIdx] = v;
        }
    }
}

// N2: blocks 0..1535     -> WfWfc row k (feat_w row k @ Wfc)
//     blocks 1536..1649  -> 114 dot tasks vs Wfc (K2, M3f, M4f, dbfc)
//     blocks 1650..1905  -> token projections p,q,r1,r2 for token (blk-1650)
__global__ __launch_bounds__(256) void k2_wfwfc_dots_tok(const float* __restrict__ feat_w,
                                                         const float* __restrict__ cls_w,
                                                         const float* __restrict__ feat_b,
                                                         const float* __restrict__ hidden,
                                                         float* __restrict__ ws) {
    const float* Wfc = ws + WFC_OFF;
    int blk = blockIdx.x, tid = threadIdx.x;
    int wave = tid >> 6, lane = tid & 63;
    if (blk < H2) {
        float acc[CC] = {};
        const float* arow = feat_w + (size_t)blk * H2;
        for (int r = tid; r < H2; r += 256) {
            float w = arow[r];
            const float* brow = Wfc + r * CC;
#pragma unroll
            for (int c = 0; c < CC; ++c) acc[c] += w * brow[c];
        }
#pragma unroll
        for (int c = 0; c < CC; ++c)
#pragma unroll
            for (int off = 32; off > 0; off >>= 1) acc[c] += __shfl_down(acc[c], off, 64);
        __shared__ float sred[4][CC];
        if (lane == 0)
#pragma unroll
            for (int c = 0; c < CC; ++c) sred[wave][c] = acc[c];
        __syncthreads();
        if (tid < CC)
            ws[WFWFC_OFF + blk * CC + tid] = sred[0][tid] + sred[1][tid] + sred[2][tid] + sred[3][tid];
    } else if (blk < H2 + 114) {
        int task = blk - H2;   // 0..113
        const float* va;
        int c, outIdx;
        if (task < 108) {
            int m = task / 36, e = task % 36, cp = e / CC;
            c = e % CC;
            int row = (m == 0) ? (H2 + 2 * CC) : ((m == 1) ? H2 : (H2 + CC)); // K2:W5, M3f:W3, M4f:W4
            va = feat_w + (size_t)(row + cp) * H2;
            outIdx = (m + 3) * 36 + e;  // 108 / 144 / 180
        } else {
            c = task - 108;
            va = feat_b;
            outIdx = 222 + c;
        }
        float acc = 0.f;
        for (int r = tid; r < H2; r += 256) acc += va[r] * Wfc[r * CC + c];
#pragma unroll
        for (int off = 32; off > 0; off >>= 1) acc += __shfl_down(acc, off, 64);
        __shared__ float sred1[4];
        if (lane == 0) sred1[wave] = acc;
        __syncthreads();
        if (tid == 0) ws[SM_OFF + outIdx] = sred1[0] + sred1[1] + sred1[2] + sred1[3];
    } else {
        // token projections p,q,r1,r2
        int tok = blk - (H2 + 114);
        float acc[4][CC] = {};
        const float* hrow = hidden + (size_t)tok * HH;
        for (int k = tid; k < HH; k += 256) {
            float hk = hrow[k];
            const float* c0 = cls_w + k * CC;
            const float* c1 = cls_w + (HH + k) * CC;
            const float* w0 = Wfc + k * CC;
            const float* w1 = Wfc + (HH + k) * CC;
#pragma unroll
            for (int c = 0; c < CC; ++c) {
                acc[0][c] += hk * c0[c];
                acc[1][c] += hk * c1[c];
                acc[2][c] += hk * w0[c];
                acc[3][c] += hk * w1[c];
            }
        }
#pragma unroll
        for (int g = 0; g < 4; ++g)
#pragma unroll
            for (int c = 0; c < CC; ++c)
#pragma unroll
                for (int off = 32; off > 0; off >>= 1) acc[g][c] += __shfl_down(acc[g][c], off, 64);
        __shared__ float sred2[4][4][CC];
        if (lane == 0)
#pragma unroll
            for (int g = 0; g < 4; ++g)
#pragma unroll
                for (int c = 0; c < CC; ++c) sred2[wave][g][c] = acc[g][c];
        __syncthreads();
        if (tid < 24) {
            int g = tid / CC, c = tid % CC;
            ws[TOK_OFF + g * (NTOK * CC) + tok * CC + c] =
                sred2[0][g][c] + sred2[1][g][c] + sred2[2][g][c] + sred2[3][g][c];
        }
    }
}

// N3: 256 blocks -> token projections s1,s2 vs WfWfc (hidden is L2-warm from N2)
__global__ __launch_bounds__(256) void k3_tok_s(const float* __restrict__ hidden,
                                                float* __restrict__ ws) {
    const float* Wf2 = ws + WFWFC_OFF;
    int tok = blockIdx.x, tid = threadIdx.x;
    int wave = tid >> 6, lane = tid & 63;
    float acc[2][CC] = {};
    const float* hrow = hidden + (size_t)tok * HH;
    for (int k = tid; k < HH; k += 256) {
        float hk = hrow[k];
        const float* v0 = Wf2 + k * CC;
        const float* v1 = Wf2 + (HH + k) * CC;
#pragma unroll
        for (int c = 0; c < CC; ++c) {
            acc[0][c] += hk * v0[c];
            acc[1][c] += hk * v1[c];
        }
    }
#pragma unroll
    for (int g = 0; g < 2; ++g)
#pragma unroll
        for (int c = 0; c < CC; ++c)
#pragma unroll
            for (int off = 32; off > 0; off >>= 1) acc[g][c] += __shfl_down(acc[g][c], off, 64);
    __shared__ float sred[4][2][CC];
    if (lane == 0)
#pragma unroll
        for (int g = 0; g < 2; ++g)
#pragma unroll
            for (int c = 0; c < CC; ++c) sred[wave][g][c] = acc[g][c];
    __syncthreads();
    if (tid < 12) {
        int g = tid / CC, c = tid % CC;
        ws[TOK_OFF + (4 + g) * (NTOK * CC) + tok * CC + c] =
            sred[0][g][c] + sred[1][g][c] + sred[2][g][c] + sred[3][g][c];
    }
}

// N4: 2 blocks x 1024 threads. Per batch: combos (on idle threads) + pooled0 ->
// alpha/beta -> pooled1 -> Afin/Bfin (LDS) -> full output tile write.
__global__ __launch_bounds__(1024) void k4_plane_out(const float* __restrict__ mask_in,
                                                     const float* __restrict__ cls_b_g,
                                                     const float* __restrict__ ws,
                                                     float* __restrict__ out) {
    int b = blockIdx.x;
    int tid = threadIdx.x;
    int t = tid / CC, c = tid % CC;   // valid for tid < 768
    __shared__ float p_sh[LL][CC], q_sh[LL][CC], m_sh[LL], cb_sh[CC];
    __shared__ float sm_sh[240];
    __shared__ float pool0[LL][CC], al[LL][CC], be[LL][CC], pool1[LL][CC];
    __shared__ float Af[LL][CC], Bf[LL][CC];
    const float* tokbase = ws + TOK_OFF;
    int tok = b * LL + t;
    if (tid < 768) {
        p_sh[t][c] = tokbase[0 * (NTOK * CC) + tok * CC + c];
        q_sh[t][c] = tokbase[1 * (NTOK * CC) + tok * CC + c];
    }
    if (tid < LL) m_sh[tid] = mask_in[b * LL + tid];
    if (tid < 240) sm_sh[tid] = ws[SM_OFF + tid];  // 228..239 garbage; overwritten below
    if (tid < CC) cb_sh[tid] = cls_b_g[tid];
    __syncthreads();
    // Phase A: pooled0 (t<768)  ||  gamma on idle threads 768..773
    if (tid < 768) {
        float pt = p_sh[t][c], qt = q_sh[t][c], cb = cb_sh[c], mt = m_sh[t];
        float best = -INFINITY;
        for (int i = 0; i < LL; ++i) {
            float mi = m_sh[i];
            float col = (i <= t) ? (p_sh[i][c] + qt + cb) * (mi * mt) : 0.0f;
            float row = (t <= i) ? (pt + q_sh[i][c] + cb) * (mt * mi) : 0.0f;
            best = fmaxf(best, fmaxf(col, row));
        }
        pool0[t][c] = best;
    } else if (tid < 768 + CC) {
        int cg = tid - 768;
        float g = sm_sh[216 + cg];  // d1
        for (int cp = 0; cp < CC; ++cp) g += cb_sh[cp] * sm_sh[0 + cp * CC + cg];  // cls_b@K1
        sm_sh[228 + cg] = g;        // gamma
    }
    __syncthreads();
    // Phase B: alpha/beta  ||  Cfin on idle threads
    if (tid < 768) {
        float a = tokbase[2 * (NTOK * CC) + tok * CC + c];
        float bv = tokbase[3 * (NTOK * CC) + tok * CC + c];
        for (int cp = 0; cp < CC; ++cp) {
            float p0 = pool0[t][cp];
            a  += p0 * sm_sh[36 + cp * CC + c] + p_sh[t][cp] * sm_sh[0 + cp * CC + c];
            bv += p0 * sm_sh[72 + cp * CC + c] + q_sh[t][cp] * sm_sh[0 + cp * CC + c];
        }
        al[t][c] = a;
        be[t][c] = bv;
    } else if (tid < 768 + CC) {
        int cg = tid - 768;
        float f = sm_sh[222 + cg] + sm_sh[216 + cg];   // dbfc + d1
        for (int cp = 0; cp < CC; ++cp) f += cb_sh[cp] * sm_sh[108 + cp * CC + cg];   // cls_b@K2
        for (int cp = 0; cp < CC; ++cp) f += sm_sh[228 + cp] * sm_sh[0 + cp * CC + cg]; // gamma@K1
        sm_sh[234 + cg] = f;        // Cfin
    }
    __syncthreads();
    // Phase C: pooled1 on probs1 = alpha_i + beta_j + gamma
    if (tid < 768) {
        float at = al[t][c], bt = be[t][c], g = sm_sh[228 + c], mt = m_sh[t];
        float best = -INFINITY;
        for (int i = 0; i < LL; ++i) {
            float mi = m_sh[i];
            float col = (i <= t) ? (al[i][c] + bt + g) * (mi * mt) : 0.0f;
            float row = (t <= i) ? (at + be[i][c] + g) * (mt * mi) : 0.0f;
            best = fmaxf(best, fmaxf(col, row));
        }
        pool1[t][c] = best;
    }
    __syncthreads();
    // Phase D: Afin/Bfin into LDS
    if (tid < 768) {
        float A = tokbase[4 * (NTOK * CC) + tok * CC + c];
        float Bv = tokbase[5 * (NTOK * CC) + tok * CC + c];
        for (int cp = 0; cp < CC; ++cp) {
            float p0 = pool0[t][cp], p1 = pool1[t][cp];
            A  += p0 * sm_sh[144 + cp * CC + c] + p1 * sm_sh[36 + cp * CC + c]
                + p_sh[t][cp] * sm_sh[108 + cp * CC + c] + al[t][cp] * sm_sh[0 + cp * CC + c];
            Bv += p0 * sm_sh[180 + cp * CC + c] + p1 * sm_sh[72 + cp * CC + c]
                + q_sh[t][cp] * sm_sh[108 + cp * CC + c] + be[t][cp] * sm_sh[0 + cp * CC + c];
        }
        Af[t][c] = A;
        Bf[t][c] = Bv;
    }
    __syncthreads();
    // Phase E: write out[b,i,j,c] = Af[i][c] + Bf[j][c] + Cfin[c], vectorized float4
    {
        float* obase = out + (size_t)b * (LL * LL * CC);
        const int NV = (LL * LL * CC) / 4;   // 24576
        for (int v = tid; v < NV; v += 1024) {
            int r = v * 4;
            int i = r / (LL * CC);           // 4-groups never straddle i (768 % 4 == 0)
            int rem = r - i * (LL * CC);
            int j = rem / CC, cc0 = rem - j * CC;
            float4 o;
            float* op = &o.x;
            int jj = j, cc = cc0;
#pragma unroll
            for (int k2 = 0; k2 < 4; ++k2) {
                op[k2] = Af[i][cc] + Bf[jj][cc] + sm_sh[234 + cc];
                if (++cc == CC) { cc = 0; ++jj; }
            }
            *(float4*)(obase + r) = o;
        }
    }
}

// ---------------------------------------------------------------------------
extern "C" void kernel_launch(void* const* d_in, const int* in_sizes, int n_in,
                              void* d_out, int out_size, void* d_ws, size_t ws_size,
                              hipStream_t stream) {
    const float* hidden = (const float*)d_in[0];          // (2,128,768)
    const float* attention_mask = (const float*)d_in[1];  // (2,128)
    const float* cls_w = (const float*)d_in[2];           // (1536,6)
    const float* cls_b = (const float*)d_in[3];           // (6,)
    const float* feat_w = (const float*)d_in[4];          // (1554,1536)
    const float* feat_b = (const float*)d_in[5];          // (1536,)
    // d_in[6] = nhops, fixed at 2
    float* out = (float*)d_out;
    float* ws = (float*)d_ws;

    k1_wfc_dots<<<H2 + 114, 256, 0, stream>>>(feat_w, cls_w, cls_b, feat_b, ws);
    k2_wfwfc_dots_tok<<<H2 + 114 + NTOK, 256, 0, stream>>>(feat_w, cls_w, feat_b, hidden, ws);
    k3_tok_s<<<NTOK, 256, 0, stream>>>(hidden, ws);
    k4_plane_out<<<BB, 1024, 0, stream>>>(attention_mask, cls_b, ws, out);
}